// Round 15
// baseline (301.986 us; speedup 1.0000x reference)
//
#include <hip/hip_runtime.h>

#define NN 384
#define NF 512
#define NH 192
#define NC 64

typedef __bf16 bf16x8 __attribute__((ext_vector_type(8)));
typedef float f32x4 __attribute__((ext_vector_type(4)));

static __device__ __forceinline__ float b2f(unsigned short u) {
  union { unsigned int i; float f; } v; v.i = ((unsigned int)u) << 16; return v.f;
}
static __device__ __forceinline__ unsigned short f2b(float f) {
  unsigned int u = __float_as_uint(f);
  unsigned int r = (u + 0x7FFFu + ((u >> 16) & 1u)) >> 16;
  return (unsigned short)r;
}

// A: x_init = x@W_emb + b_emb ; t1 = x_init@W1 ; uT = bf16(x_init)^T
// 2 rows/block (grid 192)
__global__ void __launch_bounds__(192) k_emb(
    const float* __restrict__ x, const float* __restrict__ W_emb,
    const float* __restrict__ b_emb, const float* __restrict__ W1,
    float* __restrict__ xinit, float* __restrict__ t1,
    unsigned short* __restrict__ uT)
{
  __shared__ float xl[2][NF];
  __shared__ float xi[2][NH];
  const int r0 = blockIdx.x * 2;
  const int tid = threadIdx.x;
#pragma unroll
  for (int rr = 0; rr < 2; ++rr)
    for (int k = tid; k < NF; k += 192)
      xl[rr][k] = x[(size_t)(r0 + rr) * NF + k];
  __syncthreads();
  const int h = tid;
  float a0 = b_emb[h], a1 = a0;
  for (int k = 0; k < NF; ++k) {
    float w = W_emb[k * NH + h];
    a0 += xl[0][k] * w; a1 += xl[1][k] * w;
  }
  float acc[2] = {a0, a1};
#pragma unroll
  for (int rr = 0; rr < 2; ++rr) {
    xinit[(r0 + rr) * NH + h] = acc[rr];
    xi[rr][h] = acc[rr];
    uT[h * NN + (r0 + rr)] = f2b(acc[rr]);
  }
  __syncthreads();
  float c0 = 0.f, c1 = 0.f;
  for (int k = 0; k < NH; ++k) {
    float w = W1[k * NH + h];
    c0 += xi[0][k] * w; c1 += xi[1][k] * w;
  }
  t1[(r0 + 0) * NH + h] = c0;
  t1[(r0 + 1) * NH + h] = c1;
}

// C: x1 = relu(adj@t1 + b1) ; vT = bf16(x1)^T   (2 rows/block, grid 192)
__global__ void __launch_bounds__(192) k_gc1(
    const float* __restrict__ adj, const float* __restrict__ t1,
    const float* __restrict__ b1, float* __restrict__ x1,
    unsigned short* __restrict__ vT)
{
  __shared__ float al[2][NN];
  const int r0 = blockIdx.x * 2;
  const int tid = threadIdx.x;
#pragma unroll
  for (int rr = 0; rr < 2; ++rr)
    for (int j = tid; j < NN; j += 192)
      al[rr][j] = adj[(size_t)(r0 + rr) * NN + j];
  __syncthreads();
  const int h = tid;
  float a0 = b1[h], a1 = a0;
  for (int j = 0; j < NN; ++j) {
    float t = t1[j * NH + h];
    a0 += al[0][j] * t; a1 += al[1][j] * t;
  }
  float acc[2] = {a0, a1};
#pragma unroll
  for (int rr = 0; rr < 2; ++rr) {
    float v = fmaxf(acc[rr], 0.f);
    x1[(r0 + rr) * NH + h] = v;
    vT[h * NN + (r0 + rr)] = f2b(v);
  }
}

// D: E0 = adj1 @ outer(u,u), E1 = adj1 @ outer(v,v). BARRIER-FREE streaming.
// Operand-swapped MFMA (R7-proven-correct math): M^T = U^T * A_r^T, so adj1
// rows feed the B-operand directly global->register (32B contiguous/lane),
// zero LDS / zero barriers / zero swizzle in the main loop.
// grid 1152 = 384 r x 3 ig (128 rows). 8 waves = rg2 x hg2 x uv2, each wave
// INDEPENDENT: 2 temporal passes x (32 i-rows x 6 h-tiles x full K=384).
// R7's two diagnosed failures fixed: uf (U^T tiles) ping-pong prefetched
// 1 iter ahead (no dependent L2 chain); acc[2][6]=48 VGPR + launch_bounds
// (512,1) -> ~210 VGPR, no spill, 2 waves/SIMD. A ring-3, prefetch 2 ahead.
// Compiler-managed waits only (no inline asm). Final 3KB LDS reduce.
__global__ void __launch_bounds__(512, 1) k_edge(
    const float* __restrict__ adj1, const unsigned short* __restrict__ uT,
    const unsigned short* __restrict__ vT,
    float* __restrict__ E0p, float* __restrict__ E1p)
{
  __shared__ float red[2][2][2][96];   // [uv][hg][rg][h-local]

  const int tid = threadIdx.x;
  const int wv = tid >> 6, l = tid & 63;
  const int lr = l & 15, lg = l >> 4;
  const int rg = wv >> 2, hg = (wv >> 1) & 1, uv = wv & 1;
  const int r = blockIdx.x / 3, ig = blockIdx.x - r * 3;
  const float* __restrict__ Ar = adj1 + (size_t)r * (NN * NN);
  const unsigned short* __restrict__ selT = uv ? vT : uT;

  // uf sources: row (hg*6+t)*16+lr of U^T, k-window +lg*8 (16B contiguous)
  const unsigned short* ufp[6];
#pragma unroll
  for (int t = 0; t < 6; ++t)
    ufp[t] = selT + ((hg * 6 + t) * 16 + lr) * NN + lg * 8;

  float e[6][4];
#pragma unroll
  for (int t = 0; t < 6; ++t)
#pragma unroll
    for (int q = 0; q < 4; ++q) e[t][q] = 0.f;

#pragma unroll
  for (int p = 0; p < 2; ++p) {
    const int i0p = ig * 128 + rg * 64 + p * 32;
    const float* arow0 = Ar + (size_t)(i0p + lr) * NN + lg * 8;
    const float* arow1 = Ar + (size_t)(i0p + 16 + lr) * NN + lg * 8;

    f32x4 A[3][2][2];    // [ring slot][s2][half] -- static idx under unroll
    bf16x8 uf[2][6];
    f32x4 acc[2][6];
    const f32x4 zero = {0.f, 0.f, 0.f, 0.f};
#pragma unroll
    for (int s = 0; s < 2; ++s)
#pragma unroll
      for (int t = 0; t < 6; ++t) acc[s][t] = zero;

    // prologue: A(0), A(1), uf(0)
#pragma unroll
    for (int s = 0; s < 2; ++s) {
      const float* ar = s ? arow1 : arow0;
      A[0][s][0] = *reinterpret_cast<const f32x4*>(ar);
      A[0][s][1] = *reinterpret_cast<const f32x4*>(ar + 4);
      A[1][s][0] = *reinterpret_cast<const f32x4*>(ar + 32);
      A[1][s][1] = *reinterpret_cast<const f32x4*>(ar + 36);
    }
#pragma unroll
    for (int t = 0; t < 6; ++t)
      uf[0][t] = *reinterpret_cast<const bf16x8*>(ufp[t]);

#pragma unroll
    for (int n = 0; n < 12; ++n) {
      // prefetch A(n+2) into ring slot (consumed 2 iters later)
      if (n < 10) {
        const int kb2 = (n + 2) * 32;
#pragma unroll
        for (int s = 0; s < 2; ++s) {
          const float* ar = (s ? arow1 : arow0) + kb2;
          A[(n + 2) % 3][s][0] = *reinterpret_cast<const f32x4*>(ar);
          A[(n + 2) % 3][s][1] = *reinterpret_cast<const f32x4*>(ar + 4);
        }
      }
      // prefetch uf(n+1) (consumed next iter)
      if (n < 11) {
        const int kb1 = (n + 1) * 32;
#pragma unroll
        for (int t = 0; t < 6; ++t)
          uf[(n + 1) & 1][t] = *reinterpret_cast<const bf16x8*>(ufp[t] + kb1);
      }
      // compute iter n
      bf16x8 af[2];
#pragma unroll
      for (int s = 0; s < 2; ++s) {
        f32x4 q0 = A[n % 3][s][0], q1 = A[n % 3][s][1];
        af[s][0] = (__bf16)q0[0]; af[s][1] = (__bf16)q0[1];
        af[s][2] = (__bf16)q0[2]; af[s][3] = (__bf16)q0[3];
        af[s][4] = (__bf16)q1[0]; af[s][5] = (__bf16)q1[1];
        af[s][6] = (__bf16)q1[2]; af[s][7] = (__bf16)q1[3];
      }
#pragma unroll
      for (int t = 0; t < 6; ++t) {
        acc[0][t] = __builtin_amdgcn_mfma_f32_16x16x32_bf16(uf[n & 1][t], af[0], acc[0][t], 0, 0, 0);
        acc[1][t] = __builtin_amdgcn_mfma_f32_16x16x32_bf16(uf[n & 1][t], af[1], acc[1][t], 0, 0, 0);
      }
    }

    // fold this pass (R7-verified mapping): acc elem q: h=(hg*6+t)*16+lg*4+q,
    // i = i0p + s2*16 + lr
#pragma unroll
    for (int t = 0; t < 6; ++t) {
#pragma unroll
      for (int q = 0; q < 4; ++q) {
        const int h = (hg * 6 + t) * 16 + lg * 4 + q;
        e[t][q] += b2f(selT[h * NN + i0p + lr]) * acc[0][t][q]
                 + b2f(selT[h * NN + i0p + 16 + lr]) * acc[1][t][q];
      }
    }
  }

  // reduce over lr (16 lanes within each lg group)
#pragma unroll
  for (int t = 0; t < 6; ++t)
#pragma unroll
    for (int q = 0; q < 4; ++q) {
      float s = e[t][q];
      s += __shfl_xor(s, 1); s += __shfl_xor(s, 2);
      s += __shfl_xor(s, 4); s += __shfl_xor(s, 8);
      e[t][q] = s;
    }
  if (lr == 0) {
#pragma unroll
    for (int t = 0; t < 6; ++t)
#pragma unroll
      for (int q = 0; q < 4; ++q)
        red[uv][hg][rg][t * 16 + lg * 4 + q] = e[t][q];
  }
  __syncthreads();
  if (tid < 384) {
    const int uvx = tid / 192, rem = tid - uvx * 192;
    const int hgx = rem / 96, o = rem - hgx * 96;
    const int h = hgx * 96 + o;
    float val = red[uvx][hgx][0][o] + red[uvx][hgx][1][o];
    float* Ep = uvx ? E1p : E0p;
    Ep[((size_t)ig * NN + r) * NH + h] = val;
  }
}

// E: x_e = relu(E0@We+be); xs = x1+x_e+x_init; t2 = xs@W2; xe2 = (E0+E1)@We2+be2
// 2 rows/block (grid 192). t2 aliases E0p plane0, xe2 plane1.
__global__ void __launch_bounds__(192) k_mid(
    const float* __restrict__ E0p, const float* __restrict__ E1p,
    const float* __restrict__ x1, const float* __restrict__ xinit,
    const float* __restrict__ We, const float* __restrict__ be,
    const float* __restrict__ W2, const float* __restrict__ We2,
    const float* __restrict__ be2, float* __restrict__ t2,
    float* __restrict__ xe2)
{
  __shared__ float e0l[2][NH], s01[2][NH], xsl[2][NH];
  const int r0 = blockIdx.x * 2;
  const int h = threadIdx.x;
#pragma unroll
  for (int rr = 0; rr < 2; ++rr) {
    const int idx = (r0 + rr) * NH + h;
    float e0v = E0p[idx] + E0p[NN * NH + idx] + E0p[2 * NN * NH + idx];
    float e1v = E1p[idx] + E1p[NN * NH + idx] + E1p[2 * NN * NH + idx];
    e0l[rr][h] = e0v;
    s01[rr][h] = e0v + e1v;
  }
  __syncthreads();
  float x0 = be[h], x1a = x0;
  for (int k = 0; k < NH; ++k) {
    float w = We[k * NH + h];
    x0 += e0l[0][k] * w; x1a += e0l[1][k] * w;
  }
  float xe[2] = {x0, x1a};
#pragma unroll
  for (int rr = 0; rr < 2; ++rr) {
    const int idx = (r0 + rr) * NH + h;
    xsl[rr][h] = fmaxf(xe[rr], 0.f) + x1[idx] + xinit[idx];
  }
  __syncthreads();
  float t0 = 0.f, t1v = 0.f;
  float b0 = be2[h], b1v = b0;
  for (int k = 0; k < NH; ++k) {
    float w2 = W2[k * NH + h];
    float w3 = We2[k * NH + h];
    t0 += xsl[0][k] * w2; t1v += xsl[1][k] * w2;
    b0 += s01[0][k] * w3; b1v += s01[1][k] * w3;
  }
  t2[(r0 + 0) * NH + h] = t0;  t2[(r0 + 1) * NH + h] = t1v;
  xe2[(r0 + 0) * NH + h] = b0; xe2[(r0 + 1) * NH + h] = b1v;
}

// F: x_mid = adj@t2 + b2; h = relu(x_mid + xe2); logits = h@W_cls + b_cls;
// log_softmax. 2 rows/block (grid 192).
__global__ void __launch_bounds__(256) k_out(
    const float* __restrict__ adj, const float* __restrict__ t2,
    const float* __restrict__ b2, const float* __restrict__ xe2,
    const float* __restrict__ Wc, const float* __restrict__ bc,
    float* __restrict__ out)
{
  __shared__ float al[2][NN];
  __shared__ float hl[2][NH];
  const int r0 = blockIdx.x * 2;
  const int tid = threadIdx.x;
#pragma unroll
  for (int rr = 0; rr < 2; ++rr)
    for (int j = tid; j < NN; j += 256)
      al[rr][j] = adj[(size_t)(r0 + rr) * NN + j];
  __syncthreads();
  if (tid < NH) {
    const int h = tid;
    float a0 = b2[h], a1 = a0;
    for (int j = 0; j < NN; ++j) {
      float t = t2[j * NH + h];
      a0 += al[0][j] * t; a1 += al[1][j] * t;
    }
    float acc[2] = {a0, a1};
#pragma unroll
    for (int rr = 0; rr < 2; ++rr)
      hl[rr][h] = fmaxf(acc[rr] + xe2[(r0 + rr) * NH + h], 0.f);
  }
  __syncthreads();
  const int w = tid >> 6, lane = tid & 63;
  if (w < 2) {
    float lgt = bc[lane];
    for (int k = 0; k < NH; ++k) lgt += hl[w][k] * Wc[k * NC + lane];
    float m = lgt;
#pragma unroll
    for (int off = 32; off >= 1; off >>= 1) m = fmaxf(m, __shfl_xor(m, off));
    float s = expf(lgt - m);
#pragma unroll
    for (int off = 32; off >= 1; off >>= 1) s += __shfl_xor(s, off);
    out[(size_t)(r0 + w) * NC + lane] = lgt - m - logf(s);
  }
}

extern "C" void kernel_launch(void* const* d_in, const int* in_sizes, int n_in,
                              void* d_out, int out_size, void* d_ws, size_t ws_size,
                              hipStream_t stream) {
  const float* x     = (const float*)d_in[0];
  const float* adj   = (const float*)d_in[1];
  const float* adj1  = (const float*)d_in[2];
  const float* W_emb = (const float*)d_in[3];
  const float* b_emb = (const float*)d_in[4];
  const float* W_cls = (const float*)d_in[5];
  const float* b_cls = (const float*)d_in[6];
  const float* W1    = (const float*)d_in[7];
  const float* b1    = (const float*)d_in[8];
  const float* W2    = (const float*)d_in[9];
  const float* b2    = (const float*)d_in[10];
  const float* We    = (const float*)d_in[11];
  const float* be    = (const float*)d_in[12];
  const float* We2   = (const float*)d_in[13];
  const float* be2   = (const float*)d_in[14];

  // ws layout (total 2,949,120 B -- identical to the proven footprint)
  char* ws = (char*)d_ws;
  float* xinit = (float*)(ws + 0);
  float* t1    = (float*)(ws + 294912);
  float* x1    = (float*)(ws + 589824);
  float* E0p   = (float*)(ws + 884736);      // [3][384*192] f32
  float* E1p   = (float*)(ws + 1769472);     // [3][384*192] f32
  unsigned short* uT = (unsigned short*)(ws + 2654208);  // [192][384] bf16
  unsigned short* vT = (unsigned short*)(ws + 2801664);  // [192][384] bf16
  float* t2  = E0p;
  float* xe2 = E0p + NN * NH;

  k_emb<<<192, 192, 0, stream>>>(x, W_emb, b_emb, W1, xinit, t1, uT);
  k_gc1<<<192, 192, 0, stream>>>(adj, t1, b1, x1, vT);
  k_edge<<<1152, 512, 0, stream>>>(adj1, uT, vT, E0p, E1p);
  k_mid<<<192, 192, 0, stream>>>(E0p, E1p, x1, xinit, We, be, W2, We2, be2, t2, xe2);
  k_out<<<192, 256, 0, stream>>>(adj, t2, b2, xe2, W_cls, b_cls, (float*)d_out);
}

// Round 16
// 163.288 us; speedup vs baseline: 1.8494x; 1.8494x over previous
//
#include <hip/hip_runtime.h>

#define NN 384
#define NF 512
#define NH 192
#define NC 64

typedef __bf16 bf16x8 __attribute__((ext_vector_type(8)));
typedef float f32x4 __attribute__((ext_vector_type(4)));

static __device__ __forceinline__ float b2f(unsigned short u) {
  union { unsigned int i; float f; } v; v.i = ((unsigned int)u) << 16; return v.f;
}
static __device__ __forceinline__ unsigned short f2b(float f) {
  unsigned int u = __float_as_uint(f);
  unsigned int r = (u + 0x7FFFu + ((u >> 16) & 1u)) >> 16;
  return (unsigned short)r;
}

// A: x_init = x@W_emb + b_emb ; t1 = x_init@W1 ; uT = bf16(x_init)^T
// 2 rows/block (grid 192): halves the serial k-loop cost per block.
__global__ void __launch_bounds__(192) k_emb(
    const float* __restrict__ x, const float* __restrict__ W_emb,
    const float* __restrict__ b_emb, const float* __restrict__ W1,
    float* __restrict__ xinit, float* __restrict__ t1,
    unsigned short* __restrict__ uT)
{
  __shared__ float xl[2][NF];
  __shared__ float xi[2][NH];
  const int r0 = blockIdx.x * 2;
  const int tid = threadIdx.x;
#pragma unroll
  for (int rr = 0; rr < 2; ++rr)
    for (int k = tid; k < NF; k += 192)
      xl[rr][k] = x[(size_t)(r0 + rr) * NF + k];
  __syncthreads();
  const int h = tid;
  float a0 = b_emb[h], a1 = a0;
  for (int k = 0; k < NF; ++k) {
    float w = W_emb[k * NH + h];
    a0 += xl[0][k] * w; a1 += xl[1][k] * w;
  }
  float acc[2] = {a0, a1};
#pragma unroll
  for (int rr = 0; rr < 2; ++rr) {
    xinit[(r0 + rr) * NH + h] = acc[rr];
    xi[rr][h] = acc[rr];
    uT[h * NN + (r0 + rr)] = f2b(acc[rr]);
  }
  __syncthreads();
  float c0 = 0.f, c1 = 0.f;
  for (int k = 0; k < NH; ++k) {
    float w = W1[k * NH + h];
    c0 += xi[0][k] * w; c1 += xi[1][k] * w;
  }
  t1[(r0 + 0) * NH + h] = c0;
  t1[(r0 + 1) * NH + h] = c1;
}

// C: x1 = relu(adj@t1 + b1) ; vT = bf16(x1)^T   (2 rows/block, grid 192)
__global__ void __launch_bounds__(192) k_gc1(
    const float* __restrict__ adj, const float* __restrict__ t1,
    const float* __restrict__ b1, float* __restrict__ x1,
    unsigned short* __restrict__ vT)
{
  __shared__ float al[2][NN];
  const int r0 = blockIdx.x * 2;
  const int tid = threadIdx.x;
#pragma unroll
  for (int rr = 0; rr < 2; ++rr)
    for (int j = tid; j < NN; j += 192)
      al[rr][j] = adj[(size_t)(r0 + rr) * NN + j];
  __syncthreads();
  const int h = tid;
  float a0 = b1[h], a1 = a0;
  for (int j = 0; j < NN; ++j) {
    float t = t1[j * NH + h];
    a0 += al[0][j] * t; a1 += al[1][j] * t;
  }
  float acc[2] = {a0, a1};
#pragma unroll
  for (int rr = 0; rr < 2; ++rr) {
    float v = fmaxf(acc[rr], 0.f);
    x1[(r0 + rr) * NH + h] = v;
    vT[h * NN + (r0 + rr)] = f2b(v);
  }
}

// D: E0 = adj1 @ outer(u,u), E1 = adj1 @ outer(v,v). Single HBM pass.
// Proven best (R13, 137us): counted-vmcnt 4-slot ring, depth-3 prefetch,
// grid 1152 = 384r x 3ig, 8 waves rg2 x hg2 x uv2, 24 MFMA/wave/chunk.
// Wait schedule exact: per-wave VMEM = 5/STAGE; outstanding stages at top of
// chunk g = 3 for g<=9 (vmcnt(10)), 2 at g=10 (vmcnt(5)), 1 at g=11
// (vmcnt(0)). STAGE(g+3) for g<=8 writes slot (g+3)%4 = (g-1)%4, last read
// at chunk g-1 strictly before this chunk's barrier.
__global__ void __launch_bounds__(512, 2) k_edge(
    const float* __restrict__ adj1, const unsigned short* __restrict__ uT,
    const unsigned short* __restrict__ vT,
    float* __restrict__ E0p, float* __restrict__ E1p)
{
  // 4 slots x (A 16KB + B 24KB) = 160KB
  __shared__ __align__(16) unsigned char lds_raw[163840];

  const int tid = threadIdx.x;
  const int wv = tid >> 6, l = tid & 63;
  const int lr = l & 15, lg = l >> 4;
  const int rg = wv >> 2, hg = (wv >> 1) & 1, uv = wv & 1;
  const int bid = blockIdx.x;
  const int r = bid / 3, ig = bid - r * 3;
  const int i0 = ig * 128;
  const float* __restrict__ Ar = adj1 + (size_t)r * (NN * NN);
  const unsigned short* __restrict__ selT = uv ? vT : uT;

  const int aunit = (l & 7) ^ (l >> 3);        // A source 16B-unit pre-swizzle
  const int bunit = (l & 3) ^ ((l >> 3) & 3);  // B source 16B-unit pre-swizzle

  f32x4 acc[4][6];
  const f32x4 zero = {0.f, 0.f, 0.f, 0.f};
#pragma unroll
  for (int s = 0; s < 4; ++s)
#pragma unroll
    for (int t = 0; t < 6; ++t) acc[s][t] = zero;

  // Stage one 32-k chunk into ring slot: exactly 5 global_load_lds per wave.
  auto STAGE = [&](int slot, int kb) {
    float* As = (float*)(lds_raw + slot * 40960);
    unsigned short* Bs = (unsigned short*)(lds_raw + slot * 40960 + 16384);
    // A chunk: 128 rows x 32 f32. Wave stages rows [wv*16, +16).
#pragma unroll
    for (int p = 0; p < 2; ++p) {
      const int rowbase = wv * 16 + p * 8;
      const float* g = Ar + (size_t)(i0 + rowbase + (l >> 3)) * NN + kb + 4 * aunit;
      __builtin_amdgcn_global_load_lds(
          (const __attribute__((address_space(1))) unsigned int*)g,
          (__attribute__((address_space(3))) unsigned int*)(As + rowbase * 32),
          16, 0, 0);
    }
    // B chunk: u and v, 192 h x 32 k bf16 each. 24 wave-issues of 16 h-rows.
#pragma unroll
    for (int q = 0; q < 3; ++q) {
      const int m = wv * 3 + q;
      const int uvs = (m >= 12) ? 1 : 0;
      const int H0 = (m - uvs * 12) * 16;
      const unsigned short* src =
          (uvs ? vT : uT) + (H0 + (l >> 2)) * NN + kb + 8 * bunit;
      __builtin_amdgcn_global_load_lds(
          (const __attribute__((address_space(1))) unsigned int*)src,
          (__attribute__((address_space(3))) unsigned int*)(Bs + uvs * 6144 + H0 * 32),
          16, 0, 0);
    }
  };

  // prologue: depth-3 prefetch (slots 0,1,2 in flight; 15 VMEM outstanding)
  STAGE(0, 0);
  STAGE(1, 32);
  STAGE(2, 64);

#pragma unroll
  for (int kk = 0; kk < 12; ++kk) {
    // retire OWN stage kk; leave later stages in flight.
    if (kk <= 9)       asm volatile("s_waitcnt vmcnt(10)" ::: "memory");
    else if (kk == 10) asm volatile("s_waitcnt vmcnt(5)" ::: "memory");
    else               asm volatile("s_waitcnt vmcnt(0)" ::: "memory");
    __builtin_amdgcn_sched_barrier(0);
    __builtin_amdgcn_s_barrier();

    const int slot = kk & 3;
    const float* Ab = (const float*)(lds_raw + slot * 40960);
    const unsigned short* Bb =
        (const unsigned short*)(lds_raw + slot * 40960 + 16384) + uv * 6144;

    bf16x8 bfr[6];
#pragma unroll
    for (int t = 0; t < 6; ++t) {
      const int h = (hg * 6 + t) * 16 + lr;
      bfr[t] = *reinterpret_cast<const bf16x8*>(Bb + h * 32 + 8 * (lg ^ ((lr >> 1) & 3)));
    }
#pragma unroll
    for (int s = 0; s < 4; ++s) {
      const int R = rg * 64 + s * 16 + lr;
      const float* rowp = Ab + R * 32;
      f32x4 q0 = *reinterpret_cast<const f32x4*>(rowp + 4 * ((2 * lg) ^ (lr & 7)));
      f32x4 q1 = *reinterpret_cast<const f32x4*>(rowp + 4 * (((2 * lg) + 1) ^ (lr & 7)));
      bf16x8 af;
      af[0] = (__bf16)q0[0]; af[1] = (__bf16)q0[1];
      af[2] = (__bf16)q0[2]; af[3] = (__bf16)q0[3];
      af[4] = (__bf16)q1[0]; af[5] = (__bf16)q1[1];
      af[6] = (__bf16)q1[2]; af[7] = (__bf16)q1[3];
#pragma unroll
      for (int t = 0; t < 6; ++t)
        acc[s][t] = __builtin_amdgcn_mfma_f32_16x16x32_bf16(af, bfr[t], acc[s][t], 0, 0, 0);
    }

    // stage chunk kk+3 into the slot last read at chunk kk-1 (safe: all waves
    // finished reading it strictly before the barrier above).
    if (kk <= 8) STAGE((kk + 3) & 3, (kk + 3) * 32);
  }

  // epilogue (R4/R10-verified): e[h] = sum_i w[i,h]*M[i,h]; frag elem q:
  // i = i0+rg*64+s*16+lg*4+q, h = (hg*6+t)*16+lr. shfl-reduce over lg,
  // LDS-reduce over rg, write partial plane ig.
  float e[6];
#pragma unroll
  for (int t = 0; t < 6; ++t) {
    const int h = (hg * 6 + t) * 16 + lr;
    float ac = 0.f;
#pragma unroll
    for (int s = 0; s < 4; ++s) {
      const int ii = i0 + rg * 64 + s * 16 + lg * 4;
      ushort4 w4 = *reinterpret_cast<const ushort4*>(selT + h * NN + ii);
      ac += b2f(w4.x) * acc[s][t][0] + b2f(w4.y) * acc[s][t][1]
          + b2f(w4.z) * acc[s][t][2] + b2f(w4.w) * acc[s][t][3];
    }
    ac += __shfl_xor(ac, 16);
    ac += __shfl_xor(ac, 32);
    e[t] = ac;
  }
  __syncthreads();                       // all compute done before LDS reuse
  float* scratch = (float*)lds_raw;      // [2][192]
  if (rg == 1 && lg == 0) {
#pragma unroll
    for (int t = 0; t < 6; ++t)
      scratch[uv * 192 + (hg * 6 + t) * 16 + lr] = e[t];
  }
  __syncthreads();
  if (rg == 0 && lg == 0) {
    float* Ep = uv ? E1p : E0p;
#pragma unroll
    for (int t = 0; t < 6; ++t) {
      const int h = (hg * 6 + t) * 16 + lr;
      Ep[((size_t)ig * NN + r) * NH + h] = e[t] + scratch[uv * 192 + h];
    }
  }
}

// E: x_e = relu(E0@We+be); xs = x1+x_e+x_init; t2 = xs@W2; xe2 = (E0+E1)@We2+be2
// 2 rows/block (grid 192). t2 aliases E0p plane0, xe2 plane1 (reads complete
// before writes within each block; blocks touch disjoint rows).
__global__ void __launch_bounds__(192) k_mid(
    const float* __restrict__ E0p, const float* __restrict__ E1p,
    const float* __restrict__ x1, const float* __restrict__ xinit,
    const float* __restrict__ We, const float* __restrict__ be,
    const float* __restrict__ W2, const float* __restrict__ We2,
    const float* __restrict__ be2, float* __restrict__ t2,
    float* __restrict__ xe2)
{
  __shared__ float e0l[2][NH], s01[2][NH], xsl[2][NH];
  const int r0 = blockIdx.x * 2;
  const int h = threadIdx.x;
#pragma unroll
  for (int rr = 0; rr < 2; ++rr) {
    const int idx = (r0 + rr) * NH + h;
    float e0v = E0p[idx] + E0p[NN * NH + idx] + E0p[2 * NN * NH + idx];
    float e1v = E1p[idx] + E1p[NN * NH + idx] + E1p[2 * NN * NH + idx];
    e0l[rr][h] = e0v;
    s01[rr][h] = e0v + e1v;
  }
  __syncthreads();
  float x0 = be[h], x1a = x0;
  for (int k = 0; k < NH; ++k) {
    float w = We[k * NH + h];
    x0 += e0l[0][k] * w; x1a += e0l[1][k] * w;
  }
  float xe[2] = {x0, x1a};
#pragma unroll
  for (int rr = 0; rr < 2; ++rr) {
    const int idx = (r0 + rr) * NH + h;
    xsl[rr][h] = fmaxf(xe[rr], 0.f) + x1[idx] + xinit[idx];
  }
  __syncthreads();
  float t0 = 0.f, t1v = 0.f;
  float b0 = be2[h], b1v = b0;
  for (int k = 0; k < NH; ++k) {
    float w2 = W2[k * NH + h];
    float w3 = We2[k * NH + h];
    t0 += xsl[0][k] * w2; t1v += xsl[1][k] * w2;
    b0 += s01[0][k] * w3; b1v += s01[1][k] * w3;
  }
  t2[(r0 + 0) * NH + h] = t0;  t2[(r0 + 1) * NH + h] = t1v;
  xe2[(r0 + 0) * NH + h] = b0; xe2[(r0 + 1) * NH + h] = b1v;
}

// F: x_mid = adj@t2 + b2; h = relu(x_mid + xe2); logits = h@W_cls + b_cls;
// log_softmax. 2 rows/block (grid 192).
__global__ void __launch_bounds__(256) k_out(
    const float* __restrict__ adj, const float* __restrict__ t2,
    const float* __restrict__ b2, const float* __restrict__ xe2,
    const float* __restrict__ Wc, const float* __restrict__ bc,
    float* __restrict__ out)
{
  __shared__ float al[2][NN];
  __shared__ float hl[2][NH];
  const int r0 = blockIdx.x * 2;
  const int tid = threadIdx.x;
#pragma unroll
  for (int rr = 0; rr < 2; ++rr)
    for (int j = tid; j < NN; j += 256)
      al[rr][j] = adj[(size_t)(r0 + rr) * NN + j];
  __syncthreads();
  if (tid < NH) {
    const int h = tid;
    float a0 = b2[h], a1 = a0;
    for (int j = 0; j < NN; ++j) {
      float t = t2[j * NH + h];
      a0 += al[0][j] * t; a1 += al[1][j] * t;
    }
    float acc[2] = {a0, a1};
#pragma unroll
    for (int rr = 0; rr < 2; ++rr)
      hl[rr][h] = fmaxf(acc[rr] + xe2[(r0 + rr) * NH + h], 0.f);
  }
  __syncthreads();
  const int w = tid >> 6, lane = tid & 63;
  if (w < 2) {
    float lgt = bc[lane];
    for (int k = 0; k < NH; ++k) lgt += hl[w][k] * Wc[k * NC + lane];
    float m = lgt;
#pragma unroll
    for (int off = 32; off >= 1; off >>= 1) m = fmaxf(m, __shfl_xor(m, off));
    float s = expf(lgt - m);
#pragma unroll
    for (int off = 32; off >= 1; off >>= 1) s += __shfl_xor(s, off);
    out[(size_t)(r0 + w) * NC + lane] = lgt - m - logf(s);
  }
}

extern "C" void kernel_launch(void* const* d_in, const int* in_sizes, int n_in,
                              void* d_out, int out_size, void* d_ws, size_t ws_size,
                              hipStream_t stream) {
  const float* x     = (const float*)d_in[0];
  const float* adj   = (const float*)d_in[1];
  const float* adj1  = (const float*)d_in[2];
  const float* W_emb = (const float*)d_in[3];
  const float* b_emb = (const float*)d_in[4];
  const float* W_cls = (const float*)d_in[5];
  const float* b_cls = (const float*)d_in[6];
  const float* W1    = (const float*)d_in[7];
  const float* b1    = (const float*)d_in[8];
  const float* W2    = (const float*)d_in[9];
  const float* b2    = (const float*)d_in[10];
  const float* We    = (const float*)d_in[11];
  const float* be    = (const float*)d_in[12];
  const float* We2   = (const float*)d_in[13];
  const float* be2   = (const float*)d_in[14];

  // ws layout (total 2,949,120 B -- the proven footprint)
  char* ws = (char*)d_ws;
  float* xinit = (float*)(ws + 0);
  float* t1    = (float*)(ws + 294912);
  float* x1    = (float*)(ws + 589824);
  float* E0p   = (float*)(ws + 884736);      // [3][384*192] f32
  float* E1p   = (float*)(ws + 1769472);     // [3][384*192] f32
  unsigned short* uT = (unsigned short*)(ws + 2654208);  // [192][384] bf16
  unsigned short* vT = (unsigned short*)(ws + 2801664);  // [192][384] bf16
  // t2/xe2 alias E0p planes 0/1 (k_mid reads before writing; rows disjoint per block)
  float* t2  = E0p;
  float* xe2 = E0p + NN * NH;

  k_emb<<<192, 192, 0, stream>>>(x, W_emb, b_emb, W1, xinit, t1, uT);
  k_gc1<<<192, 192, 0, stream>>>(adj, t1, b1, x1, vT);
  k_edge<<<1152, 512, 0, stream>>>(adj1, uT, vT, E0p, E1p);
  k_mid<<<192, 192, 0, stream>>>(E0p, E1p, x1, xinit, We, be, W2, We2, be2, t2, xe2);
  k_out<<<192, 256, 0, stream>>>(adj, t2, b2, xe2, W_cls, b_cls, (float*)d_out);
}

// Round 17
// 161.063 us; speedup vs baseline: 1.8750x; 1.0138x over previous
//
#include <hip/hip_runtime.h>

#define NN 384
#define NF 512
#define NH 192
#define NC 64

typedef __bf16 bf16x8 __attribute__((ext_vector_type(8)));
typedef float f32x4 __attribute__((ext_vector_type(4)));

static __device__ __forceinline__ float b2f(unsigned short u) {
  union { unsigned int i; float f; } v; v.i = ((unsigned int)u) << 16; return v.f;
}
static __device__ __forceinline__ unsigned short f2b(float f) {
  unsigned int u = __float_as_uint(f);
  unsigned int r = (u + 0x7FFFu + ((u >> 16) & 1u)) >> 16;
  return (unsigned short)r;
}

// A: x_init = x@W_emb + b_emb ; t1 = x_init@W1 ; uT = bf16(x_init)^T
// 2 rows/block (grid 192)
__global__ void __launch_bounds__(192) k_emb(
    const float* __restrict__ x, const float* __restrict__ W_emb,
    const float* __restrict__ b_emb, const float* __restrict__ W1,
    float* __restrict__ xinit, float* __restrict__ t1,
    unsigned short* __restrict__ uT)
{
  __shared__ float xl[2][NF];
  __shared__ float xi[2][NH];
  const int r0 = blockIdx.x * 2;
  const int tid = threadIdx.x;
#pragma unroll
  for (int rr = 0; rr < 2; ++rr)
    for (int k = tid; k < NF; k += 192)
      xl[rr][k] = x[(size_t)(r0 + rr) * NF + k];
  __syncthreads();
  const int h = tid;
  float a0 = b_emb[h], a1 = a0;
  for (int k = 0; k < NF; ++k) {
    float w = W_emb[k * NH + h];
    a0 += xl[0][k] * w; a1 += xl[1][k] * w;
  }
  float acc[2] = {a0, a1};
#pragma unroll
  for (int rr = 0; rr < 2; ++rr) {
    xinit[(r0 + rr) * NH + h] = acc[rr];
    xi[rr][h] = acc[rr];
    uT[h * NN + (r0 + rr)] = f2b(acc[rr]);
  }
  __syncthreads();
  float c0 = 0.f, c1 = 0.f;
  for (int k = 0; k < NH; ++k) {
    float w = W1[k * NH + h];
    c0 += xi[0][k] * w; c1 += xi[1][k] * w;
  }
  t1[(r0 + 0) * NH + h] = c0;
  t1[(r0 + 1) * NH + h] = c1;
}

// C: x1 = relu(adj@t1 + b1) ; vT = bf16(x1)^T   (2 rows/block, grid 192)
__global__ void __launch_bounds__(192) k_gc1(
    const float* __restrict__ adj, const float* __restrict__ t1,
    const float* __restrict__ b1, float* __restrict__ x1,
    unsigned short* __restrict__ vT)
{
  __shared__ float al[2][NN];
  const int r0 = blockIdx.x * 2;
  const int tid = threadIdx.x;
#pragma unroll
  for (int rr = 0; rr < 2; ++rr)
    for (int j = tid; j < NN; j += 192)
      al[rr][j] = adj[(size_t)(r0 + rr) * NN + j];
  __syncthreads();
  const int h = tid;
  float a0 = b1[h], a1 = a0;
  for (int j = 0; j < NN; ++j) {
    float t = t1[j * NH + h];
    a0 += al[0][j] * t; a1 += al[1][j] * t;
  }
  float acc[2] = {a0, a1};
#pragma unroll
  for (int rr = 0; rr < 2; ++rr) {
    float v = fmaxf(acc[rr], 0.f);
    x1[(r0 + rr) * NH + h] = v;
    vT[h * NN + (r0 + rr)] = f2b(v);
  }
}

// D: E0 = adj1 @ outer(u,u), E1 = adj1 @ outer(v,v). Single HBM pass.
// R13's protocol with K=64 chunks: 6 chunks/block instead of 12 (halves the
// per-chunk-quantum cost, whatever it is), 80KB slots (A 32KB + B 48KB),
// ring-2 = 160KB LDS. Stage for chunk kk+1 issued at TOP of chunk kk (after
// the barrier: slot (kk+1)&1 = slot (kk-1)&1 whose reads all completed at
// chunk kk-1, strictly before this barrier -- same proof as R13). One full
// compute phase in flight before its vmcnt(0). Per-wave VMEM = 10/STAGE
// (4 A + 6 B); no other VMEM in the loop -> counts exact.
// grid 1152 = 384r x 3ig, 8 waves rg2 x hg2 x uv2, 48 MFMA/wave/chunk.
__global__ void __launch_bounds__(512, 2) k_edge(
    const float* __restrict__ adj1, const unsigned short* __restrict__ uT,
    const unsigned short* __restrict__ vT,
    float* __restrict__ E0p, float* __restrict__ E1p)
{
  // 2 slots x (A 32KB + B 48KB) = 160KB
  __shared__ __align__(16) unsigned char lds_raw[163840];

  const int tid = threadIdx.x;
  const int wv = tid >> 6, l = tid & 63;
  const int lr = l & 15, lg = l >> 4;
  const int rg = wv >> 2, hg = (wv >> 1) & 1, uv = wv & 1;
  const int bid = blockIdx.x;
  const int r = bid / 3, ig = bid - r * 3;
  const int i0 = ig * 128;
  const float* __restrict__ Ar = adj1 + (size_t)r * (NN * NN);
  const unsigned short* __restrict__ selT = uv ? vT : uT;

  f32x4 acc[4][6];
  const f32x4 zero = {0.f, 0.f, 0.f, 0.f};
#pragma unroll
  for (int s = 0; s < 4; ++s)
#pragma unroll
    for (int t = 0; t < 6; ++t) acc[s][t] = zero;

  // Stage one 64-k chunk (80KB): exactly 10 global_load_lds per wave.
  auto STAGE = [&](int slot, int kb) {
    float* As = (float*)(lds_raw + slot * 81920);
    unsigned short* Bs = (unsigned short*)(lds_raw + slot * 81920 + 32768);
    // A: 128 rows x 64 f32 (32KB). instr p covers 4 rows x 16 units/lane-set.
    // row = p*32 + wv*4 + (l>>4), unit u = l&15; source 16B-unit pre-swizzled
    // by ^(row&15); LDS dest linear (wave-uniform base + lane*16B).
#pragma unroll
    for (int p = 0; p < 4; ++p) {
      const int row = p * 32 + wv * 4 + (l >> 4);
      const int u = l & 15;
      const float* g = Ar + (size_t)(i0 + row) * NN + kb + 4 * (u ^ (row & 15));
      __builtin_amdgcn_global_load_lds(
          (const __attribute__((address_space(1))) unsigned int*)g,
          (__attribute__((address_space(3))) unsigned int*)(As + (p * 512 + wv * 64) * 4),
          16, 0, 0);
    }
    // B: 2 uv x 192 h x 64 k bf16 (48KB). instr j = wv*6+q covers 8 rows x
    // 8 units; row = H0+part*8+(l>>3), unit l&7, swizzle ^(l>>3) (=row&7).
#pragma unroll
    for (int q = 0; q < 6; ++q) {
      const int j = wv * 6 + q;
      const int group = j >> 1, part = j & 1;
      const int uvs = (group >= 12) ? 1 : 0;
      const int H0 = (group - uvs * 12) * 16;
      const int row = H0 + part * 8 + (l >> 3);
      const unsigned short* src =
          (uvs ? vT : uT) + row * NN + kb + 8 * ((l & 7) ^ (l >> 3));
      __builtin_amdgcn_global_load_lds(
          (const __attribute__((address_space(1))) unsigned int*)src,
          (__attribute__((address_space(3))) unsigned int*)
              (Bs + uvs * 12288 + (H0 + part * 8) * 64),
          16, 0, 0);
    }
  };

  // prologue: stage chunk 0 only (ring-2 allows depth 1)
  STAGE(0, 0);

#pragma unroll
  for (int kk = 0; kk < 6; ++kk) {
    // retire OWN stage kk (had a full compute phase in flight, kk>0)
    asm volatile("s_waitcnt vmcnt(0)" ::: "memory");
    __builtin_amdgcn_sched_barrier(0);
    __builtin_amdgcn_s_barrier();

    // stage chunk kk+1 into the other slot (its reads completed at chunk
    // kk-1, guaranteed by the barrier above). Overlaps this chunk's compute.
    if (kk < 5) STAGE((kk + 1) & 1, (kk + 1) * 64);
    __builtin_amdgcn_sched_barrier(0);

    const int slot = kk & 1;
    const float* Ab = (const float*)(lds_raw + slot * 81920);
    const unsigned short* Bb =
        (const unsigned short*)(lds_raw + slot * 81920 + 32768) + uv * 12288;

    // B fragments: row (hg*6+t)*16+lr, k-half kh; unit (kh*4+lg)^(lr&7)
    bf16x8 bfr[2][6];
#pragma unroll
    for (int kh = 0; kh < 2; ++kh)
#pragma unroll
      for (int t = 0; t < 6; ++t) {
        const int h = (hg * 6 + t) * 16 + lr;
        bfr[kh][t] = *reinterpret_cast<const bf16x8*>(
            Bb + h * 64 + 8 * ((kh * 4 + lg) ^ (lr & 7)));
      }
#pragma unroll
    for (int s = 0; s < 4; ++s) {
      const int R = rg * 64 + s * 16 + lr;
      const float* rowp = Ab + R * 64;
#pragma unroll
      for (int kh = 0; kh < 2; ++kh) {
        f32x4 q0 = *reinterpret_cast<const f32x4*>(
            rowp + 4 * ((kh * 8 + 2 * lg) ^ (R & 15)));
        f32x4 q1 = *reinterpret_cast<const f32x4*>(
            rowp + 4 * ((kh * 8 + 2 * lg + 1) ^ (R & 15)));
        bf16x8 af;
        af[0] = (__bf16)q0[0]; af[1] = (__bf16)q0[1];
        af[2] = (__bf16)q0[2]; af[3] = (__bf16)q0[3];
        af[4] = (__bf16)q1[0]; af[5] = (__bf16)q1[1];
        af[6] = (__bf16)q1[2]; af[7] = (__bf16)q1[3];
#pragma unroll
        for (int t = 0; t < 6; ++t)
          acc[s][t] = __builtin_amdgcn_mfma_f32_16x16x32_bf16(af, bfr[kh][t], acc[s][t], 0, 0, 0);
      }
    }
  }

  // epilogue (R13-verified mapping): e[h] = sum_i w[i,h]*M[i,h]; frag elem q:
  // i = i0+rg*64+s*16+lg*4+q, h = (hg*6+t)*16+lr. shfl-reduce over lg,
  // LDS-reduce over rg, write partial plane ig.
  float e[6];
#pragma unroll
  for (int t = 0; t < 6; ++t) {
    const int h = (hg * 6 + t) * 16 + lr;
    float ac = 0.f;
#pragma unroll
    for (int s = 0; s < 4; ++s) {
      const int ii = i0 + rg * 64 + s * 16 + lg * 4;
      ushort4 w4 = *reinterpret_cast<const ushort4*>(selT + h * NN + ii);
      ac += b2f(w4.x) * acc[s][t][0] + b2f(w4.y) * acc[s][t][1]
          + b2f(w4.z) * acc[s][t][2] + b2f(w4.w) * acc[s][t][3];
    }
    ac += __shfl_xor(ac, 16);
    ac += __shfl_xor(ac, 32);
    e[t] = ac;
  }
  __syncthreads();                       // all compute done before LDS reuse
  float* scratch = (float*)lds_raw;      // [2][192]
  if (rg == 1 && lg == 0) {
#pragma unroll
    for (int t = 0; t < 6; ++t)
      scratch[uv * 192 + (hg * 6 + t) * 16 + lr] = e[t];
  }
  __syncthreads();
  if (rg == 0 && lg == 0) {
    float* Ep = uv ? E1p : E0p;
#pragma unroll
    for (int t = 0; t < 6; ++t) {
      const int h = (hg * 6 + t) * 16 + lr;
      Ep[((size_t)ig * NN + r) * NH + h] = e[t] + scratch[uv * 192 + h];
    }
  }
}

// E: x_e = relu(E0@We+be); xs = x1+x_e+x_init; t2 = xs@W2; xe2 = (E0+E1)@We2+be2
// 2 rows/block (grid 192). t2 aliases E0p plane0, xe2 plane1 (reads complete
// before writes within each block; blocks touch disjoint rows).
__global__ void __launch_bounds__(192) k_mid(
    const float* __restrict__ E0p, const float* __restrict__ E1p,
    const float* __restrict__ x1, const float* __restrict__ xinit,
    const float* __restrict__ We, const float* __restrict__ be,
    const float* __restrict__ W2, const float* __restrict__ We2,
    const float* __restrict__ be2, float* __restrict__ t2,
    float* __restrict__ xe2)
{
  __shared__ float e0l[2][NH], s01[2][NH], xsl[2][NH];
  const int r0 = blockIdx.x * 2;
  const int h = threadIdx.x;
#pragma unroll
  for (int rr = 0; rr < 2; ++rr) {
    const int idx = (r0 + rr) * NH + h;
    float e0v = E0p[idx] + E0p[NN * NH + idx] + E0p[2 * NN * NH + idx];
    float e1v = E1p[idx] + E1p[NN * NH + idx] + E1p[2 * NN * NH + idx];
    e0l[rr][h] = e0v;
    s01[rr][h] = e0v + e1v;
  }
  __syncthreads();
  float x0 = be[h], x1a = x0;
  for (int k = 0; k < NH; ++k) {
    float w = We[k * NH + h];
    x0 += e0l[0][k] * w; x1a += e0l[1][k] * w;
  }
  float xe[2] = {x0, x1a};
#pragma unroll
  for (int rr = 0; rr < 2; ++rr) {
    const int idx = (r0 + rr) * NH + h;
    xsl[rr][h] = fmaxf(xe[rr], 0.f) + x1[idx] + xinit[idx];
  }
  __syncthreads();
  float t0 = 0.f, t1v = 0.f;
  float b0 = be2[h], b1v = b0;
  for (int k = 0; k < NH; ++k) {
    float w2 = W2[k * NH + h];
    float w3 = We2[k * NH + h];
    t0 += xsl[0][k] * w2; t1v += xsl[1][k] * w2;
    b0 += s01[0][k] * w3; b1v += s01[1][k] * w3;
  }
  t2[(r0 + 0) * NH + h] = t0;  t2[(r0 + 1) * NH + h] = t1v;
  xe2[(r0 + 0) * NH + h] = b0; xe2[(r0 + 1) * NH + h] = b1v;
}

// F: x_mid = adj@t2 + b2; h = relu(x_mid + xe2); logits = h@W_cls + b_cls;
// log_softmax. 2 rows/block (grid 192).
__global__ void __launch_bounds__(256) k_out(
    const float* __restrict__ adj, const float* __restrict__ t2,
    const float* __restrict__ b2, const float* __restrict__ xe2,
    const float* __restrict__ Wc, const float* __restrict__ bc,
    float* __restrict__ out)
{
  __shared__ float al[2][NN];
  __shared__ float hl[2][NH];
  const int r0 = blockIdx.x * 2;
  const int tid = threadIdx.x;
#pragma unroll
  for (int rr = 0; rr < 2; ++rr)
    for (int j = tid; j < NN; j += 256)
      al[rr][j] = adj[(size_t)(r0 + rr) * NN + j];
  __syncthreads();
  if (tid < NH) {
    const int h = tid;
    float a0 = b2[h], a1 = a0;
    for (int j = 0; j < NN; ++j) {
      float t = t2[j * NH + h];
      a0 += al[0][j] * t; a1 += al[1][j] * t;
    }
    float acc[2] = {a0, a1};
#pragma unroll
    for (int rr = 0; rr < 2; ++rr)
      hl[rr][h] = fmaxf(acc[rr] + xe2[(r0 + rr) * NH + h], 0.f);
  }
  __syncthreads();
  const int w = tid >> 6, lane = tid & 63;
  if (w < 2) {
    float lgt = bc[lane];
    for (int k = 0; k < NH; ++k) lgt += hl[w][k] * Wc[k * NC + lane];
    float m = lgt;
#pragma unroll
    for (int off = 32; off >= 1; off >>= 1) m = fmaxf(m, __shfl_xor(m, off));
    float s = expf(lgt - m);
#pragma unroll
    for (int off = 32; off >= 1; off >>= 1) s += __shfl_xor(s, off);
    out[(size_t)(r0 + w) * NC + lane] = lgt - m - logf(s);
  }
}

extern "C" void kernel_launch(void* const* d_in, const int* in_sizes, int n_in,
                              void* d_out, int out_size, void* d_ws, size_t ws_size,
                              hipStream_t stream) {
  const float* x     = (const float*)d_in[0];
  const float* adj   = (const float*)d_in[1];
  const float* adj1  = (const float*)d_in[2];
  const float* W_emb = (const float*)d_in[3];
  const float* b_emb = (const float*)d_in[4];
  const float* W_cls = (const float*)d_in[5];
  const float* b_cls = (const float*)d_in[6];
  const float* W1    = (const float*)d_in[7];
  const float* b1    = (const float*)d_in[8];
  const float* W2    = (const float*)d_in[9];
  const float* b2    = (const float*)d_in[10];
  const float* We    = (const float*)d_in[11];
  const float* be    = (const float*)d_in[12];
  const float* We2   = (const float*)d_in[13];
  const float* be2   = (const float*)d_in[14];

  // ws layout (total 2,949,120 B -- the proven footprint)
  char* ws = (char*)d_ws;
  float* xinit = (float*)(ws + 0);
  float* t1    = (float*)(ws + 294912);
  float* x1    = (float*)(ws + 589824);
  float* E0p   = (float*)(ws + 884736);      // [3][384*192] f32
  float* E1p   = (float*)(ws + 1769472);     // [3][384*192] f32
  unsigned short* uT = (unsigned short*)(ws + 2654208);  // [192][384] bf16
  unsigned short* vT = (unsigned short*)(ws + 2801664);  // [192][384] bf16
  // t2/xe2 alias E0p planes 0/1 (k_mid reads before writing; rows disjoint per block)
  float* t2  = E0p;
  float* xe2 = E0p + NN * NH;

  k_emb<<<192, 192, 0, stream>>>(x, W_emb, b_emb, W1, xinit, t1, uT);
  k_gc1<<<192, 192, 0, stream>>>(adj, t1, b1, x1, vT);
  k_edge<<<1152, 512, 0, stream>>>(adj1, uT, vT, E0p, E1p);
  k_mid<<<192, 192, 0, stream>>>(E0p, E1p, x1, xinit, We, be, W2, We2, be2, t2, xe2);
  k_out<<<192, 256, 0, stream>>>(adj, t2, b2, xe2, W_cls, b_cls, (float*)d_out);
}